// Round 10
// baseline (28.026 us; speedup 1.0000x reference)
//
#include <hip/hip_runtime.h>

// MedianBlur 5x5, fp32 in/out, reflect padding.
// u16-packed forgetful-selection median (fp16 bit patterns of nonneg values
// order as unsigned; v_pk_min_u16/v_pk_max_u16).
// R10: persistent blocks (512 blocks x 6 tiles) + T14 async-STAGE pipeline:
// tile k+1's global loads are issued right after tile k's barrier and land
// in registers while tile k's CE network runs; double-buffered LDS.

typedef unsigned short u2 __attribute__((ext_vector_type(2)));
typedef unsigned short u4 __attribute__((ext_vector_type(4)));
typedef _Float16 h2f __attribute__((ext_vector_type(2)));
typedef float f2 __attribute__((ext_vector_type(2)));

constexpr int H = 512;
constexpr int W = 512;
constexpr int HW = H * W;
constexpr int PLANES = 8 * 3;          // 24 planes -> 12 plane-pairs
constexpr int BW = 32;                 // output cols per tile
constexpr int BHR = 32;                // output rows per tile
constexpr int TXH = BW / 2;            // 16 threads in x, 2 cols each
constexpr int LW = BW + 4;             // 36
constexpr int LH = BHR + 4;            // 36
constexpr int NT = 512;
constexpr int NHALO = LH * LW;         // 1296
constexpr int NBX = W / BW;            // 16
constexpr int NBY = H / BHR;           // 16
constexpr int NTILE = NBX * NBY * (PLANES / 2);  // 3072
constexpr int NBLK = 512;
constexpr int TPB = NTILE / NBLK;      // 6 tiles per block
constexpr int CHUNK = NTILE / 8;       // 384 tiles per XCD
constexpr size_t NPIX = (size_t)PLANES * H * W;

__device__ __forceinline__ void ce(u2& a, u2& b) {
    u2 lo = __builtin_elementwise_min(a, b);   // v_pk_min_u16
    u2 hi = __builtin_elementwise_max(a, b);   // v_pk_max_u16
    a = lo;
    b = hi;
}

template<int M>
__device__ __forceinline__ void stage(u2* c) {
#pragma unroll
    for (int i = 0; i + 1 < M; i += 2) ce(c[i], c[i + 1]);
    if constexpr (M % 2 == 0) {
#pragma unroll
        for (int i = 2; i <= M - 2; i += 2) ce(c[0], c[i]);
#pragma unroll
        for (int i = 1; i <= M - 3; i += 2) ce(c[i], c[M - 1]);
    } else {
#pragma unroll
        for (int i = 2; i <= M - 3; i += 2) ce(c[0], c[i]);
        ce(c[0], c[M - 1]);
#pragma unroll
        for (int i = 1; i <= M - 2; i += 2) ce(c[i], c[M - 1]);
    }
}

// Exact rank-6-of-11 (7 discarded below / 7 above globally -> middle of 11).
__device__ __forceinline__ u2 median11(u2* d) {
    stage<11>(d);
    stage<9>(d + 1);
    stage<7>(d + 2);
    stage<5>(d + 3);
    u2 mn = __builtin_elementwise_min(d[4], d[5]);
    u2 mx = __builtin_elementwise_max(d[4], d[5]);
    return __builtin_elementwise_max(mn, __builtin_elementwise_min(mx, d[6]));
}

__device__ __forceinline__ int reflect_off(int by, int bx, int i) {
    int r = i / LW;
    int c = i - r * LW;
    int gy = by + r - 2;
    gy = (gy < 0) ? -gy : ((gy >= H) ? (2 * H - 2 - gy) : gy);
    int gx = bx + c - 2;
    gx = (gx < 0) ? -gx : ((gx >= W) ? (2 * W - 2 - gx) : gx);
    return gy * W + gx;
}

__device__ __forceinline__ void decode(int s, int& bx, int& by, int& pp) {
    bx = (s & (NBX - 1)) * BW;
    by = ((s >> 4) & (NBY - 1)) * BHR;
    pp = s >> 8;                       // plane-pair index
}

// Issue the 6 staging loads for tile s into registers (no LDS touch).
__device__ __forceinline__ void issue_loads(const float* __restrict__ in, int s,
                                            int tid, bool has2,
                                            float& A0, float& B0, float& A1,
                                            float& B1, float& A2, float& B2) {
    int bx, by, pp;
    decode(s, bx, by, pp);
    const float* __restrict__ base = in + (size_t)pp * 2 * HW;
    int o0 = reflect_off(by, bx, tid);
    int o1 = reflect_off(by, bx, tid + NT);
    int o2 = reflect_off(by, bx, has2 ? (tid + 2 * NT) : tid);
    A0 = base[o0]; B0 = base[o0 + HW];
    A1 = base[o1]; B1 = base[o1 + HW];
    A2 = base[o2]; B2 = base[o2 + HW];
}

__global__ __launch_bounds__(512)
void median5_kernel(const float* __restrict__ in, float* __restrict__ out) {
    __shared__ u2 tile[2][LH][LW];     // double-buffered halo tiles

    const int b = blockIdx.x;
    const int tid = threadIdx.x;
    const int tx = tid & (TXH - 1);    // 0..15 (covers cols 2tx, 2tx+1)
    const int ty = tid >> 4;           // 0..31 (output row)
    const bool has2 = tid < (NHALO - 2 * NT);   // 272 threads

    if (b == 0 && tid == 0) out[NPIX] = 5.0f;   // scalar second output

    // Block's 6 contiguous tiles within its XCD chunk (b&7 -> XCD).
    const int s0 = (b & 7) * CHUNK + (b >> 3) * TPB;

    float A0, B0, A1, B1, A2, B2;
    issue_loads(in, s0, tid, has2, A0, B0, A1, B1, A2, B2);

#pragma unroll 1
    for (int k = 0; k < TPB; ++k) {
        const int cs = s0 + k;
        u2(*buf)[LW] = tile[k & 1];

        // Commit staged registers to LDS (compiler waits only these loads).
        ((u2*)buf)[tid] = __builtin_bit_cast(u2, __builtin_amdgcn_cvt_pkrtz(A0, B0));
        ((u2*)buf)[tid + NT] = __builtin_bit_cast(u2, __builtin_amdgcn_cvt_pkrtz(A1, B1));
        if (has2) {
            ((u2*)buf)[tid + 2 * NT] = __builtin_bit_cast(u2, __builtin_amdgcn_cvt_pkrtz(A2, B2));
        }
        __syncthreads();

        // T14: issue next tile's loads now; they land during this compute.
        if (k + 1 < TPB) {
            issue_loads(in, cs + 1, tid, has2, A0, B0, A1, B1, A2, B2);
        }

        // ---- Compute tile cs from buf ----
        // Window: rows ty..ty+4, cols 2tx..2tx+5 (8B-aligned row segments).
        u2 w[30];                      // row-major [5][6]
#pragma unroll
        for (int rr = 0; rr < 5; ++rr) {
            const u4* rowp = (const u4*)&buf[ty + rr][2 * tx];
            u4 q0 = rowp[0];
            u4 q1 = rowp[1];
            u4 q2 = rowp[2];
            w[rr * 6 + 0] = q0.xy;
            w[rr * 6 + 1] = q0.zw;
            w[rr * 6 + 2] = q1.xy;
            w[rr * 6 + 3] = q1.zw;
            w[rr * 6 + 4] = q2.xy;
            w[rr * 6 + 5] = q2.zw;
        }

        // Shared forgetful phase on the 20 elems common to both windows
        // (cols 1..4). At every discard prior-discards+unseen <= 11 < 12.
        u2 c[14];
        c[0] = w[1];  c[1] = w[2];  c[2] = w[3];  c[3] = w[4];
        c[4] = w[7];  c[5] = w[8];  c[6] = w[9];  c[7] = w[10];
        c[8] = w[13]; c[9] = w[14]; c[10] = w[15]; c[11] = w[16];
        c[12] = w[19]; c[13] = w[20];
        stage<14>(c); c[0] = w[21];
        stage<13>(c); c[0] = w[22];
        stage<12>(c); c[0] = w[25];
        stage<11>(c); c[0] = w[26];
        stage<10>(c); c[0] = w[27];
        stage<9>(c);  c[0] = w[28];
        stage<8>(c);
        // Survivors c[1..6]; 7 shared discarded below, 7 above.

        u2 d[11];
#pragma unroll
        for (int i = 0; i < 6; ++i) d[i] = c[1 + i];
        d[6] = w[0]; d[7] = w[6]; d[8] = w[12]; d[9] = w[18]; d[10] = w[24];
        u2 med_l = median11(d);        // left output (col 2tx)

#pragma unroll
        for (int i = 0; i < 6; ++i) d[i] = c[1 + i];
        d[6] = w[5]; d[7] = w[11]; d[8] = w[17]; d[9] = w[23]; d[10] = w[29];
        u2 med_r = median11(d);        // right output (col 2tx+1)

        h2f hl = __builtin_bit_cast(h2f, med_l);
        h2f hr = __builtin_bit_cast(h2f, med_r);

        int bx, by, pp;
        decode(cs, bx, by, pp);
        float* __restrict__ oa = out + (size_t)pp * 2 * HW;
        float* __restrict__ ob = oa + HW;
        const int o = (by + ty) * W + (bx + 2 * tx);   // 8B aligned
        f2 va = { (float)hl.x, (float)hr.x };
        f2 vb = { (float)hl.y, (float)hr.y };
        *(f2*)&oa[o] = va;
        *(f2*)&ob[o] = vb;
    }
}

extern "C" void kernel_launch(void* const* d_in, const int* in_sizes, int n_in,
                              void* d_out, int out_size, void* d_ws, size_t ws_size,
                              hipStream_t stream) {
    const float* in = (const float*)d_in[0];
    float* out = (float*)d_out;

    median5_kernel<<<dim3(NBLK), dim3(NT), 0, stream>>>(in, out);
}

// Round 11
// 26.156 us; speedup vs baseline: 1.0715x; 1.0715x over previous
//
#include <hip/hip_runtime.h>

// MedianBlur 5x5, fp32 in/out, reflect padding.
// u16-packed forgetful-selection median (fp16 bit patterns of nonneg values
// order as unsigned; v_pk_min_u16/v_pk_max_u16).
// R11: identical to R9 except __launch_bounds__(512, 8) — forces VGPR<=64 so
// 8 waves/SIMD are resident (vs 4), testing the latency-bound hypothesis.

typedef unsigned short u2 __attribute__((ext_vector_type(2)));
typedef unsigned short u4 __attribute__((ext_vector_type(4)));
typedef _Float16 h2f __attribute__((ext_vector_type(2)));
typedef float f2 __attribute__((ext_vector_type(2)));

constexpr int H = 512;
constexpr int W = 512;
constexpr int PLANES = 8 * 3;          // 24 planes -> 12 plane-pairs
constexpr int BW = 32;                 // output cols per block
constexpr int BHR = 32;                // output rows per block
constexpr int TXH = BW / 2;            // 16 threads in x, 2 cols each
constexpr int LW = BW + 4;             // 36
constexpr int LH = BHR + 4;            // 36
constexpr int NT = 512;
constexpr int NHALO = LH * LW;         // 1296
constexpr int NBX = W / BW;            // 16
constexpr int NBY = H / BHR;           // 16
constexpr int NB = NBX * NBY * (PLANES / 2);  // 3072 (divisible by 8)
constexpr size_t NPIX = (size_t)PLANES * H * W;

__device__ __forceinline__ void ce(u2& a, u2& b) {
    u2 lo = __builtin_elementwise_min(a, b);   // v_pk_min_u16
    u2 hi = __builtin_elementwise_max(a, b);   // v_pk_max_u16
    a = lo;
    b = hi;
}

template<int M>
__device__ __forceinline__ void stage(u2* c) {
#pragma unroll
    for (int i = 0; i + 1 < M; i += 2) ce(c[i], c[i + 1]);
    if constexpr (M % 2 == 0) {
#pragma unroll
        for (int i = 2; i <= M - 2; i += 2) ce(c[0], c[i]);
#pragma unroll
        for (int i = 1; i <= M - 3; i += 2) ce(c[i], c[M - 1]);
    } else {
#pragma unroll
        for (int i = 2; i <= M - 3; i += 2) ce(c[0], c[i]);
        ce(c[0], c[M - 1]);
#pragma unroll
        for (int i = 1; i <= M - 2; i += 2) ce(c[i], c[M - 1]);
    }
}

// Exact rank-6-of-11 (7 discarded below / 7 above globally -> middle of 11).
__device__ __forceinline__ u2 median11(u2* d) {
    stage<11>(d);
    stage<9>(d + 1);
    stage<7>(d + 2);
    stage<5>(d + 3);
    u2 mn = __builtin_elementwise_min(d[4], d[5]);
    u2 mx = __builtin_elementwise_max(d[4], d[5]);
    return __builtin_elementwise_max(mn, __builtin_elementwise_min(mx, d[6]));
}

__device__ __forceinline__ int reflect_off(int by, int bx, int i) {
    int r = i / LW;
    int c = i - r * LW;
    int gy = by + r - 2;
    gy = (gy < 0) ? -gy : ((gy >= H) ? (2 * H - 2 - gy) : gy);
    int gx = bx + c - 2;
    gx = (gx < 0) ? -gx : ((gx >= W) ? (2 * W - 2 - gx) : gx);
    return gy * W + gx;
}

__global__ __launch_bounds__(512, 8)
void median5_kernel(const float* __restrict__ in, float* __restrict__ out) {
    __shared__ u2 tile[LH][LW];        // 36x36 plane-pair packed halo tile

    // Bijective chunked XCD swizzle (NB=3072 divisible by 8): each XCD gets
    // 384 spatially-contiguous tiles -> halo overlap reuses that XCD's L2.
    const int b = blockIdx.x;
    const int s = (b & 7) * (NB / 8) + (b >> 3);
    const int bx = (s & (NBX - 1)) * BW;
    const int by = ((s >> 4) & (NBY - 1)) * BHR;
    const int zp = (s >> 8) * 2;

    const int tid = threadIdx.x;           // 0..511
    const int tx = tid & (TXH - 1);        // 0..15 (covers cols 2tx, 2tx+1)
    const int ty = tid >> 4;               // 0..31 (output row)

    const float* __restrict__ pa = in + (size_t)zp * (H * W);
    const float* __restrict__ pb = pa + (size_t)(H * W);
    float* __restrict__ oa = out + (size_t)zp * (H * W);
    float* __restrict__ ob = oa + (size_t)(H * W);

    // Static async staging: 1296 halo elems, 512 threads -> 2 + 272.
    const int i0 = tid;
    const int i1 = tid + NT;
    const bool has2 = tid < (NHALO - 2 * NT);
    const int i2 = has2 ? (tid + 2 * NT) : tid;
    const int o0 = reflect_off(by, bx, i0);
    const int o1 = reflect_off(by, bx, i1);
    const int o2 = reflect_off(by, bx, i2);
    float a0 = pa[o0], fb0 = pb[o0];
    float a1 = pa[o1], fb1 = pb[o1];
    float a2 = pa[o2], fb2 = pb[o2];
    ((u2*)tile)[i0] = __builtin_bit_cast(u2, __builtin_amdgcn_cvt_pkrtz(a0, fb0));
    ((u2*)tile)[i1] = __builtin_bit_cast(u2, __builtin_amdgcn_cvt_pkrtz(a1, fb1));
    if (has2) {
        ((u2*)tile)[i2] = __builtin_bit_cast(u2, __builtin_amdgcn_cvt_pkrtz(a2, fb2));
    }
    __syncthreads();

    // Window: tile rows ty..ty+4, tile cols 2tx..2tx+5. Row segment of 6 u2
    // = 24B, 8B-aligned -> 3 x 8B LDS reads per row.
    u2 w[30];                              // row-major [5][6]
#pragma unroll
    for (int rr = 0; rr < 5; ++rr) {
        const u4* rowp = (const u4*)&tile[ty + rr][2 * tx];
        u4 q0 = rowp[0];
        u4 q1 = rowp[1];
        u4 q2 = rowp[2];
        w[rr * 6 + 0] = q0.xy;
        w[rr * 6 + 1] = q0.zw;
        w[rr * 6 + 2] = q1.xy;
        w[rr * 6 + 3] = q1.zw;
        w[rr * 6 + 4] = q2.xy;
        w[rr * 6 + 5] = q2.zw;
    }

    // Shared forgetful phase on the 20 elems common to both windows
    // (cols 1..4 of each row). At every discard: prior-discards + unseen
    // (remaining shared inserts + 5 exclusive) <= 11 < 12 -> safe.
    u2 c[14];
    c[0]  = w[1];  c[1]  = w[2];  c[2]  = w[3];  c[3]  = w[4];
    c[4]  = w[7];  c[5]  = w[8];  c[6]  = w[9];  c[7]  = w[10];
    c[8]  = w[13]; c[9]  = w[14]; c[10] = w[15]; c[11] = w[16];
    c[12] = w[19]; c[13] = w[20];
    stage<14>(c); c[0] = w[21];
    stage<13>(c); c[0] = w[22];
    stage<12>(c); c[0] = w[25];
    stage<11>(c); c[0] = w[26];
    stage<10>(c); c[0] = w[27];
    stage<9>(c);  c[0] = w[28];
    stage<8>(c);
    // Survivors c[1..6]; 7 shared discarded below, 7 above.

    u2 d[11];

    // Left output (col 2tx): exclusive col 0 -> w[0,6,12,18,24].
#pragma unroll
    for (int i = 0; i < 6; ++i) d[i] = c[1 + i];
    d[6] = w[0]; d[7] = w[6]; d[8] = w[12]; d[9] = w[18]; d[10] = w[24];
    u2 med_l = median11(d);

    // Right output (col 2tx+1): exclusive col 5 -> w[5,11,17,23,29].
#pragma unroll
    for (int i = 0; i < 6; ++i) d[i] = c[1 + i];
    d[6] = w[5]; d[7] = w[11]; d[8] = w[17]; d[9] = w[23]; d[10] = w[29];
    u2 med_r = median11(d);

    h2f hl = __builtin_bit_cast(h2f, med_l);
    h2f hr = __builtin_bit_cast(h2f, med_r);

    const int o = (by + ty) * W + (bx + 2 * tx);   // even -> 8B aligned
    f2 va = { (float)hl.x, (float)hr.x };
    f2 vb = { (float)hl.y, (float)hr.y };
    *(f2*)&oa[o] = va;
    *(f2*)&ob[o] = vb;

    // Scalar second output: kernel size 5.
    if (b == 0 && tid == 0) {
        out[NPIX] = 5.0f;
    }
}

extern "C" void kernel_launch(void* const* d_in, const int* in_sizes, int n_in,
                              void* d_out, int out_size, void* d_ws, size_t ws_size,
                              hipStream_t stream) {
    const float* in = (const float*)d_in[0];
    float* out = (float*)d_out;

    median5_kernel<<<dim3(NB), dim3(NT), 0, stream>>>(in, out);
}